// Round 1
// baseline (201.979 us; speedup 1.0000x reference)
//
#include <hip/hip_runtime.h>
#include <hip/hip_bf16.h>
#include <math.h>

#define MARGIN 0.3f

// Workspace layout:
//   [0]   double  total
//   [8]   uint    pos_count
//   [12]  uint    neg_count
//   [16]  float   pos_s[N]       (N = in_sizes[0])
//   [16+4N] float neg_s[N]

__global__ void compact_sigmoid_kernel(const float* __restrict__ inputs,
                                       const int* __restrict__ targets,
                                       float* __restrict__ pos_s,
                                       float* __restrict__ neg_s,
                                       unsigned int* __restrict__ pos_count,
                                       unsigned int* __restrict__ neg_count,
                                       int n) {
    int i = blockIdx.x * blockDim.x + threadIdx.x;
    if (i >= n) return;
    float x = inputs[i];
    float s = 1.0f / (1.0f + __expf(-x));
    // Use precise expf for accuracy vs reference:
    s = 1.0f / (1.0f + expf(-x));
    if (targets[i] == 1) {
        unsigned int idx = atomicAdd(pos_count, 1u);
        pos_s[idx] = s;
    } else {
        unsigned int idx = atomicAdd(neg_count, 1u);
        neg_s[idx] = s;
    }
}

__global__ __launch_bounds__(256) void pair_hinge_kernel(
        const float* __restrict__ pos_s,
        const float* __restrict__ neg_s,
        const unsigned int* __restrict__ pos_count,
        const unsigned int* __restrict__ neg_count,
        double* __restrict__ total) {
    const unsigned int P = *pos_count;
    const unsigned int Q = *neg_count;
    const unsigned int tilesI = (P + 255u) / 256u;
    const unsigned int tilesJ = (Q + 255u) / 256u;
    const unsigned int numTiles = tilesI * tilesJ;

    __shared__ float bneg[256];
    __shared__ double wsum[4];

    double dlocal = 0.0;

    for (unsigned int tile = blockIdx.x; tile < numTiles; tile += gridDim.x) {
        unsigned int ti = tile / tilesJ;
        unsigned int tj = tile - ti * tilesJ;

        unsigned int j = tj * 256u + threadIdx.x;
        bneg[threadIdx.x] = (j < Q) ? neg_s[j] : -1e30f;  // hinge -> 0
        __syncthreads();

        unsigned int i = ti * 256u + threadIdx.x;
        float si = (i < P) ? pos_s[i] : 1e30f;            // hinge -> 0

        float fsum = 0.0f;
        #pragma unroll 16
        for (int jj = 0; jj < 256; jj++) {
            float h = MARGIN - si + bneg[jj];
            fsum += fmaxf(h, 0.0f);
        }
        dlocal += (double)fsum;
        __syncthreads();
    }

    // wave (64-lane) reduction in double
    for (int off = 32; off > 0; off >>= 1)
        dlocal += __shfl_down(dlocal, off, 64);

    int lane = threadIdx.x & 63;
    int wave = threadIdx.x >> 6;
    if (lane == 0) wsum[wave] = dlocal;
    __syncthreads();
    if (threadIdx.x == 0) {
        double bsum = wsum[0] + wsum[1] + wsum[2] + wsum[3];
        atomicAdd(total, bsum);
    }
}

__global__ void finalize_kernel(const double* __restrict__ total,
                                const unsigned int* __restrict__ pos_count,
                                const unsigned int* __restrict__ neg_count,
                                float* __restrict__ out) {
    double P = (double)(*pos_count);
    double Q = (double)(*neg_count);
    out[0] = (float)(*total / (P * Q));
}

extern "C" void kernel_launch(void* const* d_in, const int* in_sizes, int n_in,
                              void* d_out, int out_size, void* d_ws, size_t ws_size,
                              hipStream_t stream) {
    const float* inputs = (const float*)d_in[0];
    const int*   targets = (const int*)d_in[1];
    float* out = (float*)d_out;
    int n = in_sizes[0];

    char* ws = (char*)d_ws;
    double*       total     = (double*)(ws + 0);
    unsigned int* pos_count = (unsigned int*)(ws + 8);
    unsigned int* neg_count = (unsigned int*)(ws + 12);
    float*        pos_s     = (float*)(ws + 16);
    float*        neg_s     = (float*)(ws + 16 + (size_t)n * sizeof(float));

    // zero header (total + counters)
    hipMemsetAsync(d_ws, 0, 16, stream);

    int blocks = (n + 255) / 256;
    compact_sigmoid_kernel<<<blocks, 256, 0, stream>>>(
        inputs, targets, pos_s, neg_s, pos_count, neg_count, n);

    pair_hinge_kernel<<<1024, 256, 0, stream>>>(
        pos_s, neg_s, pos_count, neg_count, total);

    finalize_kernel<<<1, 1, 0, stream>>>(total, pos_count, neg_count, out);
}

// Round 2
// 86.132 us; speedup vs baseline: 2.3450x; 2.3450x over previous
//
#include <hip/hip_runtime.h>
#include <hip/hip_bf16.h>
#include <math.h>

#define MARGIN 0.3f
#define N_PAIR_BLOCKS 1024

// Workspace layout (all written unconditionally every call — no memset needed):
//   [0]                 float  a[N]         (pos ? sigmoid : +1e30)
//   [4N]                float  bp[N]        (neg ? margin+sigmoid : -1e30)
//   [8N]                double partials[N_PAIR_BLOCKS]

__global__ __launch_bounds__(256) void prep_kernel(
        const float* __restrict__ inputs,
        const int* __restrict__ targets,
        float* __restrict__ a,
        float* __restrict__ bp,
        int n) {
    int i = blockIdx.x * blockDim.x + threadIdx.x;
    if (i >= n) return;
    float x = inputs[i];
    float s = 1.0f / (1.0f + expf(-x));
    int t = targets[i];
    a[i]  = (t == 1) ? s : 1e30f;            // pos side; sentinel kills hinge
    bp[i] = (t == 0) ? (MARGIN + s) : -1e30f; // neg side (margin folded in)
}

// Full N x N pair sum with sentinels: relu(bp_j - a_i).
// Tile: 1024 rows (4 regs/thread) x 256 cols (LDS). One partial per block.
__global__ __launch_bounds__(256) void pair_hinge_kernel(
        const float* __restrict__ a,
        const float* __restrict__ bp,
        double* __restrict__ partials,
        int n) {
    const int tid = threadIdx.x;
    const unsigned int tilesI = (unsigned int)((n + 1023) / 1024);
    const unsigned int tilesJ = (unsigned int)((n + 255) / 256);
    const unsigned int numTiles = tilesI * tilesJ;

    __shared__ float bs[256];
    __shared__ double wsum[4];

    double dlocal = 0.0;

    for (unsigned int tile = blockIdx.x; tile < numTiles; tile += gridDim.x) {
        unsigned int ti = tile / tilesJ;
        unsigned int tj = tile - ti * tilesJ;

        unsigned int j = tj * 256u + tid;
        bs[tid] = (j < (unsigned int)n) ? bp[j] : -1e30f;

        unsigned int i0 = ti * 1024u + tid;
        float a0 = (i0           < (unsigned int)n) ? a[i0]        : 1e30f;
        float a1 = (i0 + 256u    < (unsigned int)n) ? a[i0 + 256]  : 1e30f;
        float a2 = (i0 + 512u    < (unsigned int)n) ? a[i0 + 512]  : 1e30f;
        float a3 = (i0 + 768u    < (unsigned int)n) ? a[i0 + 768]  : 1e30f;
        __syncthreads();

        float c0 = 0.0f, c1 = 0.0f, c2 = 0.0f, c3 = 0.0f;
        #pragma unroll 8
        for (int jj = 0; jj < 256; jj++) {
            float bj = bs[jj];
            c0 += fmaxf(bj - a0, 0.0f);
            c1 += fmaxf(bj - a1, 0.0f);
            c2 += fmaxf(bj - a2, 0.0f);
            c3 += fmaxf(bj - a3, 0.0f);
        }
        dlocal += (double)c0 + (double)c1 + (double)c2 + (double)c3;
        __syncthreads();
    }

    // wave (64-lane) reduction in double
    for (int off = 32; off > 0; off >>= 1)
        dlocal += __shfl_down(dlocal, off, 64);

    int lane = tid & 63;
    int wave = tid >> 6;
    if (lane == 0) wsum[wave] = dlocal;
    __syncthreads();
    if (tid == 0)
        partials[blockIdx.x] = wsum[0] + wsum[1] + wsum[2] + wsum[3];
}

__global__ __launch_bounds__(256) void finalize_kernel(
        const double* __restrict__ partials, int nPartials,
        const int* __restrict__ targets, int n,
        float* __restrict__ out) {
    const int tid = threadIdx.x;
    __shared__ double wsumd[4];
    __shared__ int wsump[4], wsumq[4];

    double tsum = 0.0;
    for (int i = tid; i < nPartials; i += 256) tsum += partials[i];

    int pcnt = 0, qcnt = 0;
    for (int i = tid; i < n; i += 256) {
        int t = targets[i];
        pcnt += (t == 1);
        qcnt += (t == 0);
    }

    for (int off = 32; off > 0; off >>= 1) {
        tsum += __shfl_down(tsum, off, 64);
        pcnt += __shfl_down(pcnt, off, 64);
        qcnt += __shfl_down(qcnt, off, 64);
    }
    int lane = tid & 63;
    int wave = tid >> 6;
    if (lane == 0) { wsumd[wave] = tsum; wsump[wave] = pcnt; wsumq[wave] = qcnt; }
    __syncthreads();
    if (tid == 0) {
        double T = wsumd[0] + wsumd[1] + wsumd[2] + wsumd[3];
        double P = (double)(wsump[0] + wsump[1] + wsump[2] + wsump[3]);
        double Q = (double)(wsumq[0] + wsumq[1] + wsumq[2] + wsumq[3]);
        out[0] = (float)(T / (P * Q));
    }
}

extern "C" void kernel_launch(void* const* d_in, const int* in_sizes, int n_in,
                              void* d_out, int out_size, void* d_ws, size_t ws_size,
                              hipStream_t stream) {
    const float* inputs  = (const float*)d_in[0];
    const int*   targets = (const int*)d_in[1];
    float* out = (float*)d_out;
    int n = in_sizes[0];

    char* ws = (char*)d_ws;
    float*  a        = (float*)(ws);
    float*  bp       = (float*)(ws + (size_t)n * sizeof(float));
    double* partials = (double*)(ws + (size_t)2 * n * sizeof(float));

    int blocks = (n + 255) / 256;
    prep_kernel<<<blocks, 256, 0, stream>>>(inputs, targets, a, bp, n);

    pair_hinge_kernel<<<N_PAIR_BLOCKS, 256, 0, stream>>>(a, bp, partials, n);

    finalize_kernel<<<1, 256, 0, stream>>>(partials, N_PAIR_BLOCKS, targets, n, out);
}

// Round 3
// 76.660 us; speedup vs baseline: 2.6347x; 1.1236x over previous
//
#include <hip/hip_runtime.h>
#include <hip/hip_bf16.h>
#include <math.h>

#define MARGIN 0.3f
#define PAIR_BLOCKS 512

// Workspace layout:
//   [0]   double total
//   [8]   uint   pos_count
//   [12]  uint   neg_count
//   [16]  uint   done
//   [32]  float  a[N]   (compacted sigmoid of positives)
//   [32+4N] float b[N]  (compacted margin+sigmoid of negatives)

__global__ __launch_bounds__(256) void prep_compact_kernel(
        const float* __restrict__ inputs,
        const int* __restrict__ targets,
        float* __restrict__ a,
        float* __restrict__ b,
        unsigned int* __restrict__ pos_count,
        unsigned int* __restrict__ neg_count,
        int n) {
    __shared__ unsigned int wPos[4], wNeg[4];
    __shared__ unsigned int basePos, baseNeg;
    const int tid = threadIdx.x;
    const int i = blockIdx.x * 256 + tid;
    const bool valid = (i < n);
    float x = valid ? inputs[i] : 0.0f;
    int t = valid ? targets[i] : -1;
    float s = 1.0f / (1.0f + expf(-x));
    bool isPos = valid && (t == 1);
    bool isNeg = valid && (t == 0);

    unsigned long long mP = __ballot(isPos);
    unsigned long long mN = __ballot(isNeg);
    int lane = tid & 63, wave = tid >> 6;
    unsigned long long below = (1ull << lane) - 1ull;
    unsigned int pPre = (unsigned int)__popcll(mP & below);
    unsigned int nPre = (unsigned int)__popcll(mN & below);
    if (lane == 0) { wPos[wave] = (unsigned int)__popcll(mP);
                     wNeg[wave] = (unsigned int)__popcll(mN); }
    __syncthreads();
    if (tid == 0) {
        unsigned int tp = wPos[0] + wPos[1] + wPos[2] + wPos[3];
        unsigned int tn = wNeg[0] + wNeg[1] + wNeg[2] + wNeg[3];
        basePos = atomicAdd(pos_count, tp);
        baseNeg = atomicAdd(neg_count, tn);
    }
    __syncthreads();
    unsigned int wOffP = 0, wOffN = 0;
    for (int w = 0; w < wave; w++) { wOffP += wPos[w]; wOffN += wNeg[w]; }
    if (isPos) a[basePos + wOffP + pPre] = s;
    if (isNeg) b[baseNeg + wOffN + nPre] = MARGIN + s;
}

// Pair sum over compacted arrays: sum relu(b_j - a_i), i<P, j<Q.
// Tile: 512 rows (2 regs/thread) x 256 cols (LDS float4). Fused finalize.
__global__ __launch_bounds__(256) void pair_reduce_kernel(
        const float* __restrict__ a,
        const float* __restrict__ b,
        const unsigned int* __restrict__ pos_count,
        const unsigned int* __restrict__ neg_count,
        double* __restrict__ total,
        unsigned int* __restrict__ done,
        float* __restrict__ out) {
    const int tid = threadIdx.x;
    const unsigned int P = *pos_count;
    const unsigned int Q = *neg_count;
    const unsigned int tilesI = (P + 511u) / 512u;
    const unsigned int tilesJ = (Q + 255u) / 256u;
    const unsigned int numTiles = tilesI * tilesJ;

    __shared__ float4 bs4[64];
    __shared__ double wsum[4];
    float* bs = (float*)bs4;

    double dlocal = 0.0;

    for (unsigned int tile = blockIdx.x; tile < numTiles; tile += gridDim.x) {
        unsigned int ti = tile / tilesJ;
        unsigned int tj = tile - ti * tilesJ;

        unsigned int j = tj * 256u + tid;
        bs[tid] = (j < Q) ? b[j] : -1e30f;   // sentinel -> hinge 0

        unsigned int i0 = ti * 512u + tid;
        float a0 = (i0        < P) ? a[i0]       : 1e30f;
        float a1 = (i0 + 256u < P) ? a[i0 + 256] : 1e30f;
        __syncthreads();

        float c0 = 0.0f, c1 = 0.0f;
        #pragma unroll 8
        for (int q4 = 0; q4 < 64; q4++) {
            float4 b4 = bs4[q4];
            c0 += fmaxf(b4.x - a0, 0.0f);
            c0 += fmaxf(b4.y - a0, 0.0f);
            c0 += fmaxf(b4.z - a0, 0.0f);
            c0 += fmaxf(b4.w - a0, 0.0f);
            c1 += fmaxf(b4.x - a1, 0.0f);
            c1 += fmaxf(b4.y - a1, 0.0f);
            c1 += fmaxf(b4.z - a1, 0.0f);
            c1 += fmaxf(b4.w - a1, 0.0f);
        }
        dlocal += (double)c0 + (double)c1;
        __syncthreads();
    }

    // wave (64-lane) reduction in double
    for (int off = 32; off > 0; off >>= 1)
        dlocal += __shfl_down(dlocal, off, 64);

    int lane = tid & 63, wave = tid >> 6;
    if (lane == 0) wsum[wave] = dlocal;
    __syncthreads();
    if (tid == 0) {
        double bsum = wsum[0] + wsum[1] + wsum[2] + wsum[3];
        atomicAdd(total, bsum);
        __threadfence();
        unsigned int prev = atomicAdd(done, 1u);
        if (prev == gridDim.x - 1) {   // last block: finalize
            __threadfence();
            double T = atomicAdd(total, 0.0);  // coherent read
            double PQ = (double)P * (double)Q;
            out[0] = (PQ > 0.0) ? (float)(T / PQ) : 0.0f;
        }
    }
}

extern "C" void kernel_launch(void* const* d_in, const int* in_sizes, int n_in,
                              void* d_out, int out_size, void* d_ws, size_t ws_size,
                              hipStream_t stream) {
    const float* inputs  = (const float*)d_in[0];
    const int*   targets = (const int*)d_in[1];
    float* out = (float*)d_out;
    int n = in_sizes[0];

    char* ws = (char*)d_ws;
    double*       total     = (double*)(ws + 0);
    unsigned int* pos_count = (unsigned int*)(ws + 8);
    unsigned int* neg_count = (unsigned int*)(ws + 12);
    unsigned int* done      = (unsigned int*)(ws + 16);
    float*        a         = (float*)(ws + 32);
    float*        b         = (float*)(ws + 32 + (size_t)n * sizeof(float));

    // zero header (total + counters + done)
    hipMemsetAsync(d_ws, 0, 32, stream);

    int blocks = (n + 255) / 256;
    prep_compact_kernel<<<blocks, 256, 0, stream>>>(
        inputs, targets, a, b, pos_count, neg_count, n);

    pair_reduce_kernel<<<PAIR_BLOCKS, 256, 0, stream>>>(
        a, b, pos_count, neg_count, total, done, out);
}